// Round 1
// baseline (960.740 us; speedup 1.0000x reference)
//
#include <hip/hip_runtime.h>
#include <math.h>

#define DD 100
#define NEXP 9
#define GB1 1024

__device__ __forceinline__ float blo(unsigned u){
  union { unsigned i; float f; } c; c.i = u << 16; return c.f;
}
__device__ __forceinline__ float bhi(unsigned u){
  union { unsigned i; float f; } c; c.i = u & 0xFFFF0000u; return c.f;
}
__device__ __forceinline__ unsigned short f2bf(float f){
  unsigned u = __float_as_uint(f);
  unsigned r = (u + 0x7FFFu + ((u >> 16) & 1u)) >> 16;
  return (unsigned short)r;
}
__device__ __forceinline__ float pick9(int i, float mm,
    float s0, float s1, float s2, float s3,
    float c0, float c1, float c2, float c3){
  float v = mm;
  v = (i==1) ? s0 : v; v = (i==2) ? s1 : v; v = (i==3) ? s2 : v; v = (i==4) ? s3 : v;
  v = (i==5) ? c0 : v; v = (i==6) ? c1 : v; v = (i==7) ? c2 : v; v = (i==8) ? c3 : v;
  return v;
}

// ---------------- Kernel 1: fused gating + expert mix -> out matrix ----------
// 256 threads = 4 waves; each wave handles a pair of rows per iteration.
// LDS: w_gate/w_noise padded to 12 floats per 9-wide row (16B aligned float4).
__global__ __launch_bounds__(256) void k_gating(
    const float* __restrict__ memf, const float* __restrict__ recr,
    const float* __restrict__ spar, const float* __restrict__ nsrc,
    const float* __restrict__ noise, const float* __restrict__ degc,
    const float* __restrict__ wg,   const float* __restrict__ wn,
    const int*   __restrict__ degree,
    float* __restrict__ outm, float* __restrict__ partials, int B)
{
  __shared__ __align__(16) float sWG[600*12];
  __shared__ __align__(16) float sWN[600*12];
  __shared__ float sC0[DD], sC1[DD];
  __shared__ float sPart[4][18];

  for (int i = threadIdx.x; i < 5400; i += 256){
    int rowj = i / 9, e = i % 9;
    sWG[rowj*12 + e] = wg[i];
    sWN[rowj*12 + e] = wn[i];
  }
  for (int i = threadIdx.x; i < DD; i += 256){ sC0[i] = degc[2*i]; sC1[i] = degc[2*i+1]; }
  __syncthreads();

  const int wave = threadIdx.x >> 6, lane = threadIdx.x & 63;
  const int gw = blockIdx.x*4 + wave, nw = gridDim.x*4;
  const int d0 = lane, d1 = lane + 64;
  const bool h1 = (d1 < DD);
  const int dc1 = h1 ? d1 : 0;

  float ldA[9], imA[9];
  #pragma unroll
  for (int e = 0; e < 9; e++){ ldA[e] = 0.f; imA[e] = 0.f; }

  const int npair = B >> 1;
  for (int p = gw; p < npair; p += nw){
    float m[2][2], spv[2][4][2], rcv[2][4][2], nvv[2][2], ct[2][2][6];
    #pragma unroll
    for (int rw = 0; rw < 2; rw++){
      const int r = 2*p + rw;
      const int ru = __builtin_amdgcn_readfirstlane(r);
      const float* pm = memf + (size_t)ru*DD;
      const float* ps = spar + (size_t)ru*4*DD;
      const float* pr = recr + (size_t)ru*4*DD;
      const float* pn = nsrc + (size_t)ru*DD;
      float ldg = logf((float)degree[ru] + 1.0f);
      float sca = sC0[d0] + ldg*sC1[d0];
      float scb = sC0[dc1] + ldg*sC1[dc1];
      m[rw][0] = fmaxf(pm[d0], 0.f);
      m[rw][1] = h1 ? fmaxf(pm[d1], 0.f) : 0.f;
      nvv[rw][0] = pn[d0];
      nvv[rw][1] = h1 ? pn[d1] : 0.f;
      #pragma unroll
      for (int e = 0; e < 4; e++){
        spv[rw][e][0] = ps[e*DD + d0] * sca;
        spv[rw][e][1] = h1 ? ps[e*DD + d1] * scb : 0.f;
        rcv[rw][e][0] = fmaxf(pr[e*DD + d0], 0.f);
        rcv[rw][e][1] = h1 ? fmaxf(pr[e*DD + d1], 0.f) : 0.f;
      }
      #pragma unroll
      for (int sl = 0; sl < 2; sl++){
        float rs = (spv[rw][0][sl]+spv[rw][1][sl]+spv[rw][2][sl]+spv[rw][3][sl])*0.25f;
        float rr = (rcv[rw][0][sl]+rcv[rw][1][sl]+rcv[rw][2][sl]+rcv[rw][3][sl])*0.25f;
        float mm = m[rw][sl];
        ct[rw][sl][0] = mm; ct[rw][sl][1] = rs; ct[rw][sl][2] = rr;
        ct[rw][sl][3] = mm + rs + rr; ct[rw][sl][4] = mm*rs*rr; ct[rw][sl][5] = nvv[rw][sl];
      }
    }

    // GEMV partials: cat @ [w_gate | w_noise]
    float cg[2][9], cn[2][9];
    #pragma unroll
    for (int e = 0; e < 9; e++){ cg[0][e]=0.f; cg[1][e]=0.f; cn[0][e]=0.f; cn[1][e]=0.f; }
    #pragma unroll
    for (int sl = 0; sl < 2; sl++){
      const int db = sl ? dc1 : d0;
      #pragma unroll
      for (int seg = 0; seg < 6; seg++){
        const float* wgp = &sWG[(seg*DD + db)*12];
        const float* wnp = &sWN[(seg*DD + db)*12];
        float4 ga = *(const float4*)wgp;  float4 gb = *(const float4*)(wgp + 4); float g8 = wgp[8];
        float4 na = *(const float4*)wnp;  float4 nb = *(const float4*)(wnp + 4); float n8 = wnp[8];
        #pragma unroll
        for (int rw = 0; rw < 2; rw++){
          float cv = ct[rw][sl][seg];
          cg[rw][0] += cv*ga.x; cg[rw][1] += cv*ga.y; cg[rw][2] += cv*ga.z; cg[rw][3] += cv*ga.w;
          cg[rw][4] += cv*gb.x; cg[rw][5] += cv*gb.y; cg[rw][6] += cv*gb.z; cg[rw][7] += cv*gb.w;
          cg[rw][8] += cv*g8;
          cn[rw][0] += cv*na.x; cn[rw][1] += cv*na.y; cn[rw][2] += cv*na.z; cn[rw][3] += cv*na.w;
          cn[rw][4] += cv*nb.x; cn[rw][5] += cv*nb.y; cn[rw][6] += cv*nb.z; cn[rw][7] += cv*nb.w;
          cn[rw][8] += cv*n8;
        }
      }
    }

    // butterfly reduce (identical result on all lanes)
    #pragma unroll
    for (int off = 32; off > 0; off >>= 1){
      #pragma unroll
      for (int rw = 0; rw < 2; rw++){
        #pragma unroll
        for (int e = 0; e < 9; e++){
          cg[rw][e] += __shfl_xor(cg[rw][e], off, 64);
          cn[rw][e] += __shfl_xor(cn[rw][e], off, 64);
        }
      }
    }

    #pragma unroll
    for (int rw = 0; rw < 2; rw++){
      const int r = 2*p + rw;
      const int ru = __builtin_amdgcn_readfirstlane(r);
      float cl[9], sd[9], nz[9];
      #pragma unroll
      for (int e = 0; e < 9; e++){
        cl[e] = cg[rw][e];
        float x = cn[rw][e];
        float spl = fmaxf(x, 0.f) + log1pf(expf(-fabsf(x)));   // stable softplus
        sd[e] = spl + 0.01f;
        nz[e] = cl[e] + noise[(size_t)ru*9 + e] * sd[e];
      }
      // top-3 (stable, lower index wins ties)
      float v1 = -3.402823e38f, v2 = v1, v3 = v1; int i1 = -1, i2 = -1, i3 = -1;
      #pragma unroll
      for (int e = 0; e < 9; e++){
        float v = nz[e];
        if (v > v1){ v3=v2; i3=i2; v2=v1; i2=i1; v1=v; i1=e; }
        else if (v > v2){ v3=v2; i3=i2; v2=v; i2=e; }
        else if (v > v3){ v3=v; i3=e; }
      }
      (void)i3;
      float t  = expf(v2 - v1);
      float g1 = 1.f/(1.f + t);
      float g2 = t*g1;
      #pragma unroll
      for (int e = 0; e < 9; e++){
        float thr = (nz[e] > v3) ? v3 : v2;
        float z = (cl[e] - thr)/sd[e] - 0.1f;               // GATE_MEAN = 0.1
        float pr = 0.5f * erfcf(-z * 0.70710678118654752440f);
        ldA[e] += pr;
        imA[e] += (e==i1) ? g1 : ((e==i2) ? g2 : 0.f);
      }
      // expert mix: out = g1*combine[i1] + g2*combine[i2]
      float va0 = pick9(i1, m[rw][0], spv[rw][0][0],spv[rw][1][0],spv[rw][2][0],spv[rw][3][0],
                                      rcv[rw][0][0],rcv[rw][1][0],rcv[rw][2][0],rcv[rw][3][0]);
      float vb0 = pick9(i2, m[rw][0], spv[rw][0][0],spv[rw][1][0],spv[rw][2][0],spv[rw][3][0],
                                      rcv[rw][0][0],rcv[rw][1][0],rcv[rw][2][0],rcv[rw][3][0]);
      outm[(size_t)r*DD + d0] = g1*va0 + g2*vb0;
      if (h1){
        float va1 = pick9(i1, m[rw][1], spv[rw][0][1],spv[rw][1][1],spv[rw][2][1],spv[rw][3][1],
                                        rcv[rw][0][1],rcv[rw][1][1],rcv[rw][2][1],rcv[rw][3][1]);
        float vb1 = pick9(i2, m[rw][1], spv[rw][0][1],spv[rw][1][1],spv[rw][2][1],spv[rw][3][1],
                                        rcv[rw][0][1],rcv[rw][1][1],rcv[rw][2][1],rcv[rw][3][1]);
        outm[(size_t)r*DD + d1] = g1*va1 + g2*vb1;
      }
    }
  }

  if (lane == 0){
    #pragma unroll
    for (int e = 0; e < 9; e++){ sPart[wave][e] = imA[e]; sPart[wave][9+e] = ldA[e]; }
  }
  __syncthreads();
  if (threadIdx.x < 18){
    float s = sPart[0][threadIdx.x] + sPart[1][threadIdx.x]
            + sPart[2][threadIdx.x] + sPart[3][threadIdx.x];
    partials[blockIdx.x*18 + threadIdx.x] = s;
  }
}

// ---------------- Kernel 2: deterministic loss reduction ---------------------
__global__ void k_loss(const float* __restrict__ partials, int nblk,
                       float* __restrict__ dloss)
{
  __shared__ float sS[18][15];
  int t = threadIdx.x;
  if (t < 252){
    int k = t % 18, c = t / 18;   // 14 chunks
    float s = 0.f;
    for (int b = c; b < nblk; b += 14) s += partials[b*18 + k];
    sS[k][c] = s;
  }
  __syncthreads();
  if (t < 18){
    float tot = 0.f;
    #pragma unroll
    for (int c = 0; c < 14; c++) tot += sS[t][c];
    sS[t][14] = tot;
  }
  __syncthreads();
  if (t == 0){
    float mi = 0.f, ml = 0.f;
    #pragma unroll
    for (int e = 0; e < 9; e++){ mi += sS[e][14]; ml += sS[9+e][14]; }
    mi *= (1.f/9.f); ml *= (1.f/9.f);
    float vi = 0.f, vl = 0.f;
    #pragma unroll
    for (int e = 0; e < 9; e++){
      float a = sS[e][14]   - mi; vi += a*a;
      float b = sS[9+e][14] - ml; vl += b*b;
    }
    vi *= (1.f/8.f); vl *= (1.f/8.f);   // ddof=1, n=9
    *dloss = 0.4f * (vi/(mi*mi + 1e-10f) + vl/(ml*ml + 1e-10f));
  }
}

// ---------------- Kernel 3: link-prediction head -----------------------------
// 512 threads = 8 waves; each wave computes 4 edges. Weights transposed bf16
// in LDS ([d][k], stride 102 ushorts -> odd dword stride, conflict-free).
__global__ __launch_bounds__(512) void k_edge(
    const float* __restrict__ om,
    const float* __restrict__ sw, const float* __restrict__ sb,
    const float* __restrict__ dw, const float* __restrict__ db,
    const float* __restrict__ ow, const float* __restrict__ ob,
    float* __restrict__ dout, int NE)
{
  __shared__ __align__(4) unsigned short sSW[DD*102];
  __shared__ __align__(4) unsigned short sDW[DD*102];
  __shared__ float sSB[DD], sDB[DD], sOW[DD];

  for (int i = threadIdx.x; i < DD*DD; i += 512){
    int k = i / DD, d = i % DD;
    sSW[d*102 + k] = f2bf(sw[i]);
    sDW[d*102 + k] = f2bf(dw[i]);
  }
  for (int i = threadIdx.x; i < DD; i += 512){ sSB[i]=sb[i]; sDB[i]=db[i]; sOW[i]=ow[i]; }
  __syncthreads();

  const int wave = threadIdx.x >> 6, lane = threadIdx.x & 63;
  const int grp = blockIdx.x*8 + wave;
  const int e0 = grp*4;
  if (e0 >= NE) return;
  const int e0u = __builtin_amdgcn_readfirstlane(e0);
  const float* oS = om + (size_t)e0u*DD;
  const float* oP = om + ((size_t)(NE  + e0u))*DD;
  const float* oN = om + ((size_t)(2*NE + e0u))*DD;
  const int d0 = lane, d1 = lane + 64;
  const bool h1 = (d1 < DD);
  const int dc1 = h1 ? d1 : 0;

  float aS[4][2], aP[4][2], aN[4][2];
  #pragma unroll
  for (int r = 0; r < 4; r++){
    aS[r][0]=0.f; aS[r][1]=0.f; aP[r][0]=0.f; aP[r][1]=0.f; aN[r][0]=0.f; aN[r][1]=0.f;
  }

  for (int k = 0; k < DD; k += 4){
    unsigned uA = *(const unsigned*)&sSW[d0 *102 + k];
    unsigned uB = *(const unsigned*)&sSW[d0 *102 + k + 2];
    unsigned uC = *(const unsigned*)&sSW[dc1*102 + k];
    unsigned uD = *(const unsigned*)&sSW[dc1*102 + k + 2];
    unsigned uE = *(const unsigned*)&sDW[d0 *102 + k];
    unsigned uF = *(const unsigned*)&sDW[d0 *102 + k + 2];
    unsigned uG = *(const unsigned*)&sDW[dc1*102 + k];
    unsigned uH = *(const unsigned*)&sDW[dc1*102 + k + 2];
    float wS00=blo(uA), wS01=bhi(uA), wS02=blo(uB), wS03=bhi(uB);
    float wS10=blo(uC), wS11=bhi(uC), wS12=blo(uD), wS13=bhi(uD);
    float wD00=blo(uE), wD01=bhi(uE), wD02=blo(uF), wD03=bhi(uF);
    float wD10=blo(uG), wD11=bhi(uG), wD12=blo(uH), wD13=bhi(uH);
    #pragma unroll
    for (int r = 0; r < 4; r++){
      float4 ov = *(const float4*)(oS + r*DD + k);   // wave-uniform -> s_load
      float4 pv = *(const float4*)(oP + r*DD + k);
      float4 nv = *(const float4*)(oN + r*DD + k);
      aS[r][0] += ov.x*wS00 + ov.y*wS01 + ov.z*wS02 + ov.w*wS03;
      aS[r][1] += ov.x*wS10 + ov.y*wS11 + ov.z*wS12 + ov.w*wS13;
      aP[r][0] += pv.x*wD00 + pv.y*wD01 + pv.z*wD02 + pv.w*wD03;
      aP[r][1] += pv.x*wD10 + pv.y*wD11 + pv.z*wD12 + pv.w*wD13;
      aN[r][0] += nv.x*wD00 + nv.y*wD01 + nv.z*wD02 + nv.w*wD03;
      aN[r][1] += nv.x*wD10 + nv.y*wD11 + nv.z*wD12 + nv.w*wD13;
    }
  }

  float owa = sOW[d0], owb = sOW[dc1];
  float sba = sSB[d0], sbb = sSB[dc1];
  float dba = sDB[d0], dbb = sDB[dc1];
  float ob0 = ob[0];
  #pragma unroll
  for (int r = 0; r < 4; r++){
    float hs0 = aS[r][0] + sba, hp0 = aP[r][0] + dba, hn0 = aN[r][0] + dba;
    float tp = fmaxf(hs0 + hp0, 0.f)*owa;
    float tn = fmaxf(hs0 + hn0, 0.f)*owa;
    if (h1){
      float hs1 = aS[r][1] + sbb, hp1 = aP[r][1] + dbb, hn1 = aN[r][1] + dbb;
      tp += fmaxf(hs1 + hp1, 0.f)*owb;
      tn += fmaxf(hs1 + hn1, 0.f)*owb;
    }
    #pragma unroll
    for (int off = 32; off > 0; off >>= 1){
      tp += __shfl_xor(tp, off, 64);
      tn += __shfl_xor(tn, off, 64);
    }
    if (lane == 0){
      dout[e0 + r]      = tp + ob0;
      dout[NE + e0 + r] = tn + ob0;
    }
  }
}

extern "C" void kernel_launch(void* const* d_in, const int* in_sizes, int n_in,
                              void* d_out, int out_size, void* d_ws, size_t ws_size,
                              hipStream_t stream)
{
  (void)n_in; (void)out_size; (void)ws_size;
  const float* memf  = (const float*)d_in[0];
  const float* recr  = (const float*)d_in[1];
  const float* spar  = (const float*)d_in[2];
  const float* nsrc  = (const float*)d_in[3];
  const float* noise = (const float*)d_in[4];
  const float* degc  = (const float*)d_in[5];
  const float* wg    = (const float*)d_in[6];
  const float* wn    = (const float*)d_in[7];
  const float* sw    = (const float*)d_in[8];
  const float* sb    = (const float*)d_in[9];
  const float* dw    = (const float*)d_in[10];
  const float* db    = (const float*)d_in[11];
  const float* ow    = (const float*)d_in[12];
  const float* ob    = (const float*)d_in[13];
  const int*   deg   = (const int*)d_in[14];
  // d_in[15] = neg_samples (assumed 1, per setup_inputs)

  const int B  = in_sizes[0] / DD;     // 90000
  const int NE = B / 3;                // 30000
  float* outm     = (float*)d_ws;                       // B*DD floats (36 MB)
  float* partials = outm + (size_t)B*DD;                // GB1*18 floats
  float* dout     = (float*)d_out;

  k_gating<<<dim3(GB1), dim3(256), 0, stream>>>(memf, recr, spar, nsrc, noise,
                                                degc, wg, wn, deg, outm, partials, B);
  k_loss<<<dim3(1), dim3(256), 0, stream>>>(partials, GB1, dout + 2*NE);
  const int blocks2 = (NE/4 + 7) / 8;  // 938
  k_edge<<<dim3(blocks2), dim3(512), 0, stream>>>(outm, sw, sb, dw, db, ow, ob, dout, NE);
}